// Round 11
// baseline (180.639 us; speedup 1.0000x reference)
//
#include <hip/hip_runtime.h>
#include <hip/hip_bf16.h>
#include <cstdint>
#include <cstddef>

// Problem constants
#define BB 4
#define SS 2048
#define EE 1024
#define HH 16
#define DD 64
// M = BB*SS = 8192

typedef __attribute__((ext_vector_type(8))) short bf16x8;
typedef __attribute__((ext_vector_type(4))) float f32x4;

__device__ __forceinline__ short f2bf(float f) {          // RNE
    union { float f; uint32_t u; } x; x.f = f;
    uint32_t r = (x.u + 0x7fffu + ((x.u >> 16) & 1u)) >> 16;
    return (short)r;
}
__device__ __forceinline__ short f2bf_fast(float f) {     // round-half-up, for P>=0 only
    union { float f; uint32_t u; } x; x.f = f;
    return (short)((x.u + 0x8000u) >> 16);
}

// async global->LDS, 16B per lane. LDS dest wave-uniform base; HW adds lane*16.
__device__ __forceinline__ void gload16(const void* g, void* l) {
    __builtin_amdgcn_global_load_lds(
        (__attribute__((address_space(1))) uint32_t*)(uintptr_t)g,
        (__attribute__((address_space(3))) uint32_t*)(uint32_t)(uintptr_t)l,
        16, 0, 0);
}

// DPP lane move within 16-lane rows (VALU latency, no LDS)
template<int CTRL>
__device__ __forceinline__ float dppmove(float v) {
    return __int_as_float(__builtin_amdgcn_update_dpp(
        0, __float_as_int(v), CTRL, 0xf, 0xf, true));
}
#define ROW_REDUCE(vals, OP)                                             \
    _Pragma("unroll") for (int _r = 0; _r < 4; ++_r) {                   \
        vals[_r] = OP(vals[_r], dppmove<0xB1>(vals[_r]));                \
        vals[_r] = OP(vals[_r], dppmove<0x4E>(vals[_r]));                \
        vals[_r] = OP(vals[_r], dppmove<0x124>(vals[_r]));               \
        vals[_r] = OP(vals[_r], dppmove<0x128>(vals[_r]));               \
    }
__device__ __forceinline__ float opmax(float a, float b) { return fmaxf(a, b); }
__device__ __forceinline__ float opsum(float a, float b) { return a + b; }

__global__ void cast_kernel(const float* __restrict__ in, short* __restrict__ out, int n4) {
    int stride = gridDim.x * blockDim.x;
    for (int i = blockIdx.x * blockDim.x + threadIdx.x; i < n4; i += stride) {
        float4 v = reinterpret_cast<const float4*>(in)[i];
        short4 o;
        o.x = f2bf(v.x); o.y = f2bf(v.y); o.z = f2bf(v.z); o.w = f2bf(v.w);
        reinterpret_cast<short4*>(out)[i] = o;
    }
}

// in [K][N] f32 -> out [N][K] bf16 (weight transpose; tiny)
__global__ void transpose_cast_kernel(const float* __restrict__ in, short* __restrict__ out,
                                      int ncols, int nrows) {
    __shared__ float ts[32][33];
    const int t = threadIdx.x;
    const int r = t >> 3, c4 = (t & 7) * 4;
    const int n0 = blockIdx.x * 32, k0 = blockIdx.y * 32;
    float4 v = *reinterpret_cast<const float4*>(&in[(size_t)(k0 + r) * ncols + n0 + c4]);
    ts[c4 + 0][r] = v.x; ts[c4 + 1][r] = v.y; ts[c4 + 2][r] = v.z; ts[c4 + 3][r] = v.w;
    __syncthreads();
    short4 ov;
    ov.x = f2bf(ts[r][c4 + 0]); ov.y = f2bf(ts[r][c4 + 1]);
    ov.z = f2bf(ts[r][c4 + 2]); ov.w = f2bf(ts[r][c4 + 3]);
    *reinterpret_cast<short4*>(&out[(size_t)(n0 + r) * nrows + k0 + c4]) = ov;
}

// QKV GEMM, 8-phase 256x256 template (m201-style):
// BK=64, 8 waves (2M x 4N), wave tile 128x64 (8x4 frags of 16x16x32).
// LDS 128KB: [2 tile-buffers][4 chunks of 64 rows x 64 k] for A and B.
// Per iteration: 2 K-tiles, 8 phases. Phase = {ds_read quadrant frags, issue one
// 2-chunk stage (2 gload16/thr), barrier, setprio1 + 16 MFMA + setprio0,
// [counted vmcnt before closing barrier], barrier}.
// Chunk freed at phase j is staged at phase j+1 (WAR-safe via barrier lockstep);
// RAW safety: vmcnt(N) BEFORE a barrier that precedes the reads (cross-wave safe).
// Stage order S1..S8: [b1.a13][b0.a02][b0.b01][b0.b23][b0.a13][b1.a02][b1.b01][b1.b23]
// Waits: end-P8 vmcnt(8) (protects P1), end-P2 vmcnt(10) (P3), end-P4 vmcnt(8) (P5),
// end-P6 vmcnt(10) (P7). Never 0 in the loop.
__global__ __launch_bounds__(512, 1)
void gemm_qkv(const short* __restrict__ A, const short* __restrict__ Bt,
              const float* __restrict__ bias,
              short* __restrict__ Qo, short* __restrict__ Ko, short* __restrict__ Vo)
{
    __shared__ short As[2][4][4096];   // [buf][chunk: 64 rows][64 elems] 8KB chunks
    __shared__ short Bs[2][4][4096];
    const int tid  = threadIdx.x;
    const int lane = tid & 63, wid = tid >> 6;
    const int wr = wid >> 2, wc = wid & 3;     // wave tile: rows wr*128, cols wc*64
    const int l15 = lane & 15, lhi = lane >> 4;
    const int m0 = blockIdx.y * 256, n0 = blockIdx.x * 256;
    const int srow = lane >> 3;                    // 0..7: row within wave's 8-row stage slice
    const int scol = 8 * ((lane & 7) ^ srow);      // swizzled source col (elems)
    const int xorr = (l15 & 7) << 4;               // read-side XOR (bytes)

    f32x4 acc[8][4] = {};
    bf16x8 af[4][2];        // current A quadrant frags [mf][kh]
    bf16x8 bfr[2][2][2];    // two live B sets [set][nf][kh]

#define STGA(p, c0, c1, tt)                                                              \
    gload16(&A[(size_t)(m0 + (c0)*64 + wid*8 + srow) * EE + (tt)*64 + scol],             \
            (char*)&As[p][c0][0] + wid*1024);                                            \
    gload16(&A[(size_t)(m0 + (c1)*64 + wid*8 + srow) * EE + (tt)*64 + scol],             \
            (char*)&As[p][c1][0] + wid*1024);
#define STGB(p, c0, c1, tt)                                                              \
    gload16(&Bt[(size_t)(n0 + (c0)*64 + wid*8 + srow) * EE + (tt)*64 + scol],            \
            (char*)&Bs[p][c0][0] + wid*1024);                                            \
    gload16(&Bt[(size_t)(n0 + (c1)*64 + wid*8 + srow) * EE + (tt)*64 + scol],            \
            (char*)&Bs[p][c1][0] + wid*1024);
#define RDA(p, mq)                                                                       \
    _Pragma("unroll") for (int mf = 0; mf < 4; ++mf)                                     \
    _Pragma("unroll") for (int kh = 0; kh < 2; ++kh)                                     \
        af[mf][kh] = *reinterpret_cast<const bf16x8*>((const char*)&As[p][wr*2+(mq)][0]  \
            + (mf*16 + l15)*128 + ((kh*64 + lhi*16) ^ xorr));
#define RDB(p, nq, st)                                                                   \
    _Pragma("unroll") for (int nf = 0; nf < 2; ++nf)                                     \
    _Pragma("unroll") for (int kh = 0; kh < 2; ++kh)                                     \
        bfr[st][nf][kh] = *reinterpret_cast<const bf16x8*>((const char*)&Bs[p][wc][0]    \
            + ((nq)*32 + nf*16 + l15)*128 + ((kh*64 + lhi*16) ^ xorr));
#define MMA(mq, nq, st)                                                                  \
    __builtin_amdgcn_s_setprio(1);                                                       \
    _Pragma("unroll") for (int mf = 0; mf < 4; ++mf)                                     \
    _Pragma("unroll") for (int nf = 0; nf < 2; ++nf)                                     \
    _Pragma("unroll") for (int kh = 0; kh < 2; ++kh)                                     \
        acc[(mq)*4+mf][(nq)*2+nf] = __builtin_amdgcn_mfma_f32_16x16x32_bf16(             \
            af[mf][kh], bfr[st][nf][kh], acc[(mq)*4+mf][(nq)*2+nf], 0, 0, 0);            \
    __builtin_amdgcn_s_setprio(0);
#define BARS { __builtin_amdgcn_s_barrier(); __builtin_amdgcn_sched_barrier(0); }
#define VMW(n) asm volatile("s_waitcnt vmcnt(" #n ")" ::: "memory");

    // prologue: tile 0 -> buf0 (full), tile 1 -> buf1 (a0a2, b01, b23; a13 comes at P1)
    STGA(0, 0, 2, 0) STGB(0, 0, 1, 0) STGB(0, 2, 3, 0) STGA(0, 1, 3, 0)
    STGA(1, 0, 2, 1) STGB(1, 0, 1, 1) STGB(1, 2, 3, 1)
    VMW(8) BARS

    for (int i = 0; i < 8; ++i) {
        const int tb  = 2*i + 1;
        const int ta2 = (i < 7) ? 2*i + 2 : 15;   // clamp: last-iter stages reload tile 15 (never read)
        const int tb2 = (i < 7) ? 2*i + 3 : 15;
        // ---- K-tile 2i (buf0) ----
        RDA(0,0) RDB(0,0,0) STGA(1,1,3,tb)  BARS MMA(0,0,0)         BARS  // P1
        RDB(0,1,1)          STGA(0,0,2,ta2) BARS MMA(0,1,1) VMW(10) BARS  // P2
        RDA(0,1)            STGB(0,0,1,ta2) BARS MMA(1,0,0)         BARS  // P3
                            STGB(0,2,3,ta2) BARS MMA(1,1,1) VMW(8)  BARS  // P4
        // ---- K-tile 2i+1 (buf1) ----
        RDA(1,0) RDB(1,0,0) STGA(0,1,3,ta2) BARS MMA(0,0,0)         BARS  // P5
        RDB(1,1,1)          STGA(1,0,2,tb2) BARS MMA(0,1,1) VMW(10) BARS  // P6
        RDA(1,1)            STGB(1,0,1,tb2) BARS MMA(1,0,0)         BARS  // P7
                            STGB(1,2,3,tb2) BARS MMA(1,1,1) VMW(8)  BARS  // P8
    }
#undef STGA
#undef STGB
#undef RDA
#undef RDB
#undef MMA

    // epilogue: bias + QKV scatter (Q *= 0.125*log2e for exp2-domain softmax; V^T packed)
    const int part = n0 >> 10;   // block-uniform (BN=256 divides 1024): 0=q 1=k 2=v
    #pragma unroll
    for (int mm = 0; mm < 8; ++mm) {
        #pragma unroll
        for (int nn = 0; nn < 4; ++nn) {
            const int gcol = n0 + wc * 64 + nn * 16 + l15;
            const float bv = bias[gcol];
            const int e = gcol & 1023;
            const int h = e >> 6, d = e & 63;
            const int grow0 = m0 + wr * 128 + mm * 16 + lhi * 4;
            const int bidx = grow0 >> 11;
            const int s0 = grow0 & 2047;
            const int bh = bidx * HH + h;
            if (part == 2) {
                short4 pk;
                pk.x = f2bf(acc[mm][nn][0] + bv);
                pk.y = f2bf(acc[mm][nn][1] + bv);
                pk.z = f2bf(acc[mm][nn][2] + bv);
                pk.w = f2bf(acc[mm][nn][3] + bv);
                *reinterpret_cast<short4*>(&Vo[((size_t)bh * DD + d) * SS + s0]) = pk;
            } else if (part == 0) {
                #pragma unroll
                for (int r = 0; r < 4; ++r)
                    Qo[((size_t)bh * SS + s0 + r) * DD + d] = f2bf((acc[mm][nn][r] + bv) * 0.18033688f);
            } else {
                #pragma unroll
                for (int r = 0; r < 4; ++r)
                    Ko[((size_t)bh * SS + s0 + r) * DD + d] = f2bf(acc[mm][nn][r] + bv);
            }
        }
    }
}

// Proj GEMM: out = CTX[8192,1024] * WprojT[1024,1024]^T + bias, fp32 out.
// 128x128 tile, 4 waves; TRIPLE-buffered + counted vmcnt + swizzle. (frozen from R10)
__global__ __launch_bounds__(256, 2)
void gemm_proj(const short* __restrict__ A, const short* __restrict__ Bt,
               const float* __restrict__ bias, float* __restrict__ Co)
{
    __shared__ short As[3][4096];
    __shared__ short Bs[3][4096];
    const int tid  = threadIdx.x;
    const int lane = tid & 63, wid = tid >> 6;
    const int wr = wid >> 1, wc = wid & 1;
    const int l15 = lane & 15, lhi = lane >> 4;
    const int m0 = blockIdx.y * 128, n0 = blockIdx.x * 128;
    const int sr   = lane >> 2;
    const int scol = 8 * ((lane & 3) ^ ((lane >> 3) & 3));
    const int rdx  = (lhi ^ ((l15 >> 1) & 3)) << 4;

    f32x4 acc[4][4] = {};

#define PROJ_STAGE(tt, bufi)                                                     \
    {                                                                            \
        const int kk = (tt) * 32;                                                \
        _Pragma("unroll")                                                        \
        for (int p = 0; p < 2; ++p) {                                            \
            const int c = wid * 2 + p;                                           \
            gload16(&A [(size_t)(m0 + c * 16 + sr) * EE + kk + scol],            \
                    (char*)&As[bufi][0] + c * 1024);                             \
            gload16(&Bt[(size_t)(n0 + c * 16 + sr) * EE + kk + scol],            \
                    (char*)&Bs[bufi][0] + c * 1024);                             \
        }                                                                        \
    }

    PROJ_STAGE(0, 0)
    PROJ_STAGE(1, 1)
    VMW(4) BARS

    for (int kt = 0; kt < 32; ++kt) {
        const int cur = kt % 3;
        if (kt + 2 < 32) { const int nb = (kt + 2) % 3; PROJ_STAGE(kt + 2, nb) }

        bf16x8 af2[4], bf2[4];
        #pragma unroll
        for (int mm = 0; mm < 4; ++mm)
            af2[mm] = *reinterpret_cast<const bf16x8*>(
                (const char*)&As[cur][0] + (wr * 64 + mm * 16 + l15) * 64 + rdx);
        #pragma unroll
        for (int nn = 0; nn < 4; ++nn)
            bf2[nn] = *reinterpret_cast<const bf16x8*>(
                (const char*)&Bs[cur][0] + (wc * 64 + nn * 16 + l15) * 64 + rdx);
        #pragma unroll
        for (int mm = 0; mm < 4; ++mm)
            #pragma unroll
            for (int nn = 0; nn < 4; ++nn)
                acc[mm][nn] = __builtin_amdgcn_mfma_f32_16x16x32_bf16(af2[mm], bf2[nn], acc[mm][nn], 0, 0, 0);

        if (kt < 30)       { VMW(4) BARS }
        else if (kt == 30) { VMW(0) BARS }
    }
#undef PROJ_STAGE

    #pragma unroll
    for (int mm = 0; mm < 4; ++mm) {
        #pragma unroll
        for (int nn = 0; nn < 4; ++nn) {
            const int gcol = n0 + wc * 64 + nn * 16 + l15;
            const float bv = bias[gcol];
            #pragma unroll
            for (int r = 0; r < 4; ++r) {
                const int grow = m0 + wr * 64 + mm * 16 + lhi * 4 + r;
                Co[(size_t)grow * EE + gcol] = acc[mm][nn][r] + bv;
            }
        }
    }
}

// Flash attention, causal-paired + XCD-swizzled, exp2-domain ZERO-SHIFT softmax.
// LDS = exactly 32KB: Ks single 8KB, Vs double 16KB, Ps swizzled 8KB. (frozen from R8)
__global__ __launch_bounds__(256, 4)
void attn_kernel(const short* __restrict__ Q, const short* __restrict__ K,
                 const short* __restrict__ Vt, short* __restrict__ CTX)
{
    __shared__ short Ks[4096];
    __shared__ short Vs[2][4096];
    __shared__ short Ps[4][1024];
    const int tid  = threadIdx.x;
    const int lane = tid & 63, wid = tid >> 6;
    const int l15 = lane & 15, lhi = lane >> 4;
    const int bid  = blockIdx.x;
    const int bh   = (bid & 7) * 8 + ((bid >> 3) & 7);
    const int pair = bid >> 6;
    const int b = bh >> 4, h = bh & 15;
    const size_t base = (size_t)bh * (SS * DD);
    const short* VtBase = Vt + (size_t)bh * (DD * SS);
    char* const pw = (char*)&Ps[wid][0];

    const int srow = lane >> 3;
    const int scol = 8 * ((lane & 7) ^ srow);

    for (int phase = 0; phase < 2; ++phase) {
        const int t = phase ? (31 - pair) : pair;
        const int q0 = t * 64;
        const int qbase = q0 + wid * 16;

        bf16x8 qa[2];
        qa[0] = *reinterpret_cast<const bf16x8*>(&Q[base + (size_t)(qbase + l15) * DD + lhi * 8]);
        qa[1] = *reinterpret_cast<const bf16x8*>(&Q[base + (size_t)(qbase + l15) * DD + 32 + lhi * 8]);

        f32x4 o[4] = {};
        float lrow[4] = {0.f, 0.f, 0.f, 0.f};

        #pragma unroll
        for (int p = 0; p < 2; ++p) {
            const int c = wid * 2 + p;
            gload16(&K     [base + (size_t)(c * 8 + srow) * DD + scol], (char*)Ks + c * 1024);
            gload16(&VtBase[(size_t)(c * 8 + srow) * SS + scol],        (char*)&Vs[0][0] + c * 1024);
        }
        __syncthreads();

        for (int kt = 0; kt <= t; ++kt) {
            const int cur = kt & 1;

            f32x4 sc[4];
            #pragma unroll
            for (int n = 0; n < 4; ++n) {
                const int row = n * 16 + l15;
                f32x4 cacc = {};
                #pragma unroll
                for (int ks = 0; ks < 2; ++ks) {
                    const int byteoff = (ks * 64 + lhi * 16) ^ ((l15 & 7) << 4);
                    bf16x8 kb = *reinterpret_cast<const bf16x8*>((const char*)Ks + row * 128 + byteoff);
                    cacc = __builtin_amdgcn_mfma_f32_16x16x32_bf16(qa[ks], kb, cacc, 0, 0, 0);
                }
                sc[n] = cacc;
            }

            __syncthreads();   // barrier A: Ks consumed by all waves

            if (kt < t) {
                const int k1 = (kt + 1) * 64;
                #pragma unroll
                for (int p = 0; p < 2; ++p) {
                    const int c = wid * 2 + p;
                    gload16(&K     [base + (size_t)(k1 + c * 8 + srow) * DD + scol], (char*)Ks + c * 1024);
                    gload16(&VtBase[(size_t)(c * 8 + srow) * SS + k1 + scol], (char*)&Vs[cur ^ 1][0] + c * 1024);
                }
            }

            if (kt == t) {
                #pragma unroll
                for (int n = 0; n < 4; ++n) {
                    const int col = n * 16 + l15;
                    #pragma unroll
                    for (int r = 0; r < 4; ++r) {
                        const int qrow = wid * 16 + lhi * 4 + r;
                        if (col > qrow) sc[n][r] = -1e30f;
                    }
                }
            }
            #pragma unroll
            for (int n = 0; n < 4; ++n)
                #pragma unroll
                for (int r = 0; r < 4; ++r) sc[n][r] = __builtin_amdgcn_exp2f(sc[n][r]);
            #pragma unroll
            for (int n = 0; n < 4; ++n)
                #pragma unroll
                for (int r = 0; r < 4; ++r) {
                    const int q = lhi * 4 + r;
                    const int cb = (n * 32 + l15 * 2) ^ ((q & 7) << 4);
                    *reinterpret_cast<short*>(pw + q * 128 + cb) = f2bf_fast(sc[n][r]);
                }
            bf16x8 pa[2];
            #pragma unroll
            for (int ks = 0; ks < 2; ++ks)
                pa[ks] = *reinterpret_cast<const bf16x8*>(
                    pw + l15 * 128 + ((ks * 64 + lhi * 16) ^ ((l15 & 7) << 4)));
            #pragma unroll
            for (int dg = 0; dg < 4; ++dg) {
                const int row = dg * 16 + l15;
                #pragma unroll
                for (int ks = 0; ks < 2; ++ks) {
                    const int byteoff = (ks * 64 + lhi * 16) ^ ((l15 & 7) << 4);
                    bf16x8 vb = *reinterpret_cast<const bf16x8*>((const char*)&Vs[cur][0] + row * 128 + byteoff);
                    o[dg] = __builtin_amdgcn_mfma_f32_16x16x32_bf16(pa[ks], vb, o[dg], 0, 0, 0);
                }
            }
            float tsum[4];
            #pragma unroll
            for (int r = 0; r < 4; ++r)
                tsum[r] = (sc[0][r] + sc[1][r]) + (sc[2][r] + sc[3][r]);
            ROW_REDUCE(tsum, opsum)
            #pragma unroll
            for (int r = 0; r < 4; ++r) lrow[r] += tsum[r];

            __syncthreads();   // barrier B
        }

        #pragma unroll
        for (int dg = 0; dg < 4; ++dg)
            #pragma unroll
            for (int r = 0; r < 4; ++r) {
                int s = qbase + lhi * 4 + r;
                float val = o[dg][r] / lrow[r];
                CTX[(size_t)(b * SS + s) * EE + h * DD + dg * 16 + l15] = f2bf(val);
            }
    }
}

extern "C" void kernel_launch(void* const* d_in, const int* in_sizes, int n_in,
                              void* d_out, int out_size, void* d_ws, size_t ws_size,
                              hipStream_t stream) {
    const float* hs     = (const float*)d_in[0];  // [B,S,E]
    const float* attn_w = (const float*)d_in[1];  // [E,3E]
    const float* attn_b = (const float*)d_in[2];  // [3E]
    const float* proj_w = (const float*)d_in[3];  // [E,E]
    const float* proj_b = (const float*)d_in[4];  // [E]
    float* out = (float*)d_out;

    char* ws = (char*)d_ws;
    short* Xb    = (short*)(ws + 0);          // 16.78 MB bf16 X; reused as CTX
    short* WqkvT = (short*)(ws + 16777216);   //  6.29 MB [3E][E] bf16
    short* WprojT= (short*)(ws + 23068672);   //  2.10 MB [E][E] bf16
    short* Qb    = (short*)(ws + 25165824);   // 16.78 MB [B*H][S][D]
    short* Kb    = (short*)(ws + 41943040);   // 16.78 MB [B*H][S][D]
    short* Vb    = (short*)(ws + 58720256);   // 16.78 MB [B*H][D][S]  (transposed)
    short* CTX   = Xb;

    cast_kernel<<<dim3(2048), dim3(256), 0, stream>>>(hs, Xb, (BB * SS * EE) / 4);
    transpose_cast_kernel<<<dim3(3 * EE / 32, EE / 32), dim3(256), 0, stream>>>(attn_w, WqkvT, 3 * EE, EE);
    transpose_cast_kernel<<<dim3(EE / 32, EE / 32), dim3(256), 0, stream>>>(proj_w, WprojT, EE, EE);

    gemm_qkv<<<dim3(3 * EE / 256, BB * SS / 256), dim3(512), 0, stream>>>(
        Xb, WqkvT, attn_b, Qb, Kb, Vb);

    attn_kernel<<<dim3(1024), dim3(256), 0, stream>>>(Qb, Kb, Vb, CTX);

    gemm_proj<<<dim3(EE / 128, BB * SS / 128), dim3(256), 0, stream>>>(
        CTX, WprojT, proj_b, out);
}

// Round 12
// 167.847 us; speedup vs baseline: 1.0762x; 1.0762x over previous
//
#include <hip/hip_runtime.h>
#include <hip/hip_bf16.h>
#include <cstdint>
#include <cstddef>

// Problem constants
#define BB 4
#define SS 2048
#define EE 1024
#define HH 16
#define DD 64
// M = BB*SS = 8192

typedef __attribute__((ext_vector_type(8))) short bf16x8;
typedef __attribute__((ext_vector_type(4))) float f32x4;

__device__ __forceinline__ short f2bf(float f) {          // RNE
    union { float f; uint32_t u; } x; x.f = f;
    uint32_t r = (x.u + 0x7fffu + ((x.u >> 16) & 1u)) >> 16;
    return (short)r;
}
__device__ __forceinline__ short f2bf_fast(float f) {     // round-half-up, for P>=0 only
    union { float f; uint32_t u; } x; x.f = f;
    return (short)((x.u + 0x8000u) >> 16);
}

// async global->LDS, 16B per lane. LDS dest wave-uniform base; HW adds lane*16.
__device__ __forceinline__ void gload16(const void* g, void* l) {
    __builtin_amdgcn_global_load_lds(
        (__attribute__((address_space(1))) uint32_t*)(uintptr_t)g,
        (__attribute__((address_space(3))) uint32_t*)(uint32_t)(uintptr_t)l,
        16, 0, 0);
}

// counted-vmcnt barrier (T4): drain own loads down to N, then sync, then pin
// following LDS reads behind the barrier.
#define WAIT_BARRIER(N)                                          \
    asm volatile("s_waitcnt vmcnt(" #N ")" ::: "memory");        \
    __builtin_amdgcn_s_barrier();                                \
    __builtin_amdgcn_sched_barrier(0);

// DPP lane move within 16-lane rows (VALU latency, no LDS)
template<int CTRL>
__device__ __forceinline__ float dppmove(float v) {
    return __int_as_float(__builtin_amdgcn_update_dpp(
        0, __float_as_int(v), CTRL, 0xf, 0xf, true));
}
#define ROW_REDUCE(vals, OP)                                             \
    _Pragma("unroll") for (int _r = 0; _r < 4; ++_r) {                   \
        vals[_r] = OP(vals[_r], dppmove<0xB1>(vals[_r]));                \
        vals[_r] = OP(vals[_r], dppmove<0x4E>(vals[_r]));                \
        vals[_r] = OP(vals[_r], dppmove<0x124>(vals[_r]));               \
        vals[_r] = OP(vals[_r], dppmove<0x128>(vals[_r]));               \
    }
__device__ __forceinline__ float opmax(float a, float b) { return fmaxf(a, b); }
__device__ __forceinline__ float opsum(float a, float b) { return a + b; }

__global__ void cast_kernel(const float* __restrict__ in, short* __restrict__ out, int n4) {
    int stride = gridDim.x * blockDim.x;
    for (int i = blockIdx.x * blockDim.x + threadIdx.x; i < n4; i += stride) {
        float4 v = reinterpret_cast<const float4*>(in)[i];
        short4 o;
        o.x = f2bf(v.x); o.y = f2bf(v.y); o.z = f2bf(v.z); o.w = f2bf(v.w);
        reinterpret_cast<short4*>(out)[i] = o;
    }
}

// in [K][N] f32 -> out [N][K] bf16 (weight transpose; tiny)
__global__ void transpose_cast_kernel(const float* __restrict__ in, short* __restrict__ out,
                                      int ncols, int nrows) {
    __shared__ float ts[32][33];
    const int t = threadIdx.x;
    const int r = t >> 3, c4 = (t & 7) * 4;
    const int n0 = blockIdx.x * 32, k0 = blockIdx.y * 32;
    float4 v = *reinterpret_cast<const float4*>(&in[(size_t)(k0 + r) * ncols + n0 + c4]);
    ts[c4 + 0][r] = v.x; ts[c4 + 1][r] = v.y; ts[c4 + 2][r] = v.z; ts[c4 + 3][r] = v.w;
    __syncthreads();
    short4 ov;
    ov.x = f2bf(ts[r][c4 + 0]); ov.y = f2bf(ts[r][c4 + 1]);
    ov.z = f2bf(ts[r][c4 + 2]); ov.w = f2bf(ts[r][c4 + 3]);
    *reinterpret_cast<short4*>(&out[(size_t)(n0 + r) * nrows + k0 + c4]) = ov;
}

// QKV GEMM: C = X[8192,1024] * WqkvT[3072,1024]^T. Tile 128M x 256N, BK=32, 8 waves.
// TRIPLE-buffered LDS + counted vmcnt (T4). (reverted to R10 verified version)
__global__ __launch_bounds__(512, 2)
void gemm_qkv(const short* __restrict__ A, const short* __restrict__ Bt,
              const float* __restrict__ bias,
              short* __restrict__ Qo, short* __restrict__ Ko, short* __restrict__ Vo)
{
    __shared__ short As[3][4096];    // 128 rows x 32, rows of 64B
    __shared__ short Bs[3][8192];    // 256 rows x 32
    const int tid  = threadIdx.x;
    const int lane = tid & 63, wid = tid >> 6;
    const int wr = wid >> 2, wc = wid & 3;
    const int l15 = lane & 15, lhi = lane >> 4;
    const int m0 = blockIdx.y * 128, n0 = blockIdx.x * 256;
    const int sr   = lane >> 2;                              // staging row in 16-row chunk
    const int scol = 8 * ((lane & 3) ^ ((lane >> 3) & 3));   // swizzled source col (elems)
    const int rdx  = (lhi ^ ((l15 >> 1) & 3)) << 4;          // swizzled read byte offset

    f32x4 acc[4][4] = {};

#define QKV_STAGE(tt, bufi)                                                      \
    {                                                                            \
        const int kk = (tt) * 32;                                                \
        gload16(&A[(size_t)(m0 + wid * 16 + sr) * EE + kk + scol],               \
                (char*)&As[bufi][0] + wid * 1024);                               \
        gload16(&Bt[(size_t)(n0 + wid * 32 + sr) * EE + kk + scol],              \
                (char*)&Bs[bufi][0] + wid * 2048);                               \
        gload16(&Bt[(size_t)(n0 + wid * 32 + 16 + sr) * EE + kk + scol],         \
                (char*)&Bs[bufi][0] + wid * 2048 + 1024);                        \
    }

    QKV_STAGE(0, 0)
    QKV_STAGE(1, 1)
    WAIT_BARRIER(3)   // tile 0 resident; tile 1 in flight

    for (int kt = 0; kt < 32; ++kt) {
        const int cur = kt % 3;
        if (kt + 2 < 32) { const int nb = (kt + 2) % 3; QKV_STAGE(kt + 2, nb) }

        bf16x8 af[4], bfr[4];
        #pragma unroll
        for (int mm = 0; mm < 4; ++mm)
            af[mm] = *reinterpret_cast<const bf16x8*>(
                (const char*)&As[cur][0] + (wr * 64 + mm * 16 + l15) * 64 + rdx);
        #pragma unroll
        for (int nn = 0; nn < 4; ++nn)
            bfr[nn] = *reinterpret_cast<const bf16x8*>(
                (const char*)&Bs[cur][0] + (wc * 64 + nn * 16 + l15) * 64 + rdx);
        #pragma unroll
        for (int mm = 0; mm < 4; ++mm)
            #pragma unroll
            for (int nn = 0; nn < 4; ++nn)
                acc[mm][nn] = __builtin_amdgcn_mfma_f32_16x16x32_bf16(af[mm], bfr[nn], acc[mm][nn], 0, 0, 0);

        if (kt < 30)       { WAIT_BARRIER(3) }
        else if (kt == 30) { WAIT_BARRIER(0) }
    }
#undef QKV_STAGE

    const int part = n0 >> 10;   // block-uniform: 0=q 1=k 2=v
    #pragma unroll
    for (int mm = 0; mm < 4; ++mm) {
        #pragma unroll
        for (int nn = 0; nn < 4; ++nn) {
            const int gcol = n0 + wc * 64 + nn * 16 + l15;
            const float bv = bias[gcol];
            const int e = gcol & 1023;
            const int h = e >> 6, d = e & 63;
            const int grow0 = m0 + wr * 64 + mm * 16 + lhi * 4;
            const int bidx = grow0 >> 11;
            const int s0 = grow0 & 2047;
            const int bh = bidx * HH + h;
            if (part == 2) {
                short4 pk;
                pk.x = f2bf(acc[mm][nn][0] + bv);
                pk.y = f2bf(acc[mm][nn][1] + bv);
                pk.z = f2bf(acc[mm][nn][2] + bv);
                pk.w = f2bf(acc[mm][nn][3] + bv);
                *reinterpret_cast<short4*>(&Vo[((size_t)bh * DD + d) * SS + s0]) = pk;
            } else if (part == 0) {
                #pragma unroll
                for (int r = 0; r < 4; ++r)
                    Qo[((size_t)bh * SS + s0 + r) * DD + d] = f2bf((acc[mm][nn][r] + bv) * 0.18033688f);
            } else {
                #pragma unroll
                for (int r = 0; r < 4; ++r)
                    Ko[((size_t)bh * SS + s0 + r) * DD + d] = f2bf(acc[mm][nn][r] + bv);
            }
        }
    }
}

// Proj GEMM: out = CTX[8192,1024] * WprojT[1024,1024]^T + bias, fp32 out.
// 128x128 tile, 4 waves; TRIPLE-buffered + counted vmcnt + swizzle. (frozen)
__global__ __launch_bounds__(256, 2)
void gemm_proj(const short* __restrict__ A, const short* __restrict__ Bt,
               const float* __restrict__ bias, float* __restrict__ Co)
{
    __shared__ short As[3][4096];
    __shared__ short Bs[3][4096];
    const int tid  = threadIdx.x;
    const int lane = tid & 63, wid = tid >> 6;
    const int wr = wid >> 1, wc = wid & 1;
    const int l15 = lane & 15, lhi = lane >> 4;
    const int m0 = blockIdx.y * 128, n0 = blockIdx.x * 128;
    const int sr   = lane >> 2;
    const int scol = 8 * ((lane & 3) ^ ((lane >> 3) & 3));
    const int rdx  = (lhi ^ ((l15 >> 1) & 3)) << 4;

    f32x4 acc[4][4] = {};

#define PROJ_STAGE(tt, bufi)                                                     \
    {                                                                            \
        const int kk = (tt) * 32;                                                \
        _Pragma("unroll")                                                        \
        for (int p = 0; p < 2; ++p) {                                            \
            const int c = wid * 2 + p;                                           \
            gload16(&A [(size_t)(m0 + c * 16 + sr) * EE + kk + scol],            \
                    (char*)&As[bufi][0] + c * 1024);                             \
            gload16(&Bt[(size_t)(n0 + c * 16 + sr) * EE + kk + scol],            \
                    (char*)&Bs[bufi][0] + c * 1024);                             \
        }                                                                        \
    }

    PROJ_STAGE(0, 0)
    PROJ_STAGE(1, 1)
    WAIT_BARRIER(4)

    for (int kt = 0; kt < 32; ++kt) {
        const int cur = kt % 3;
        if (kt + 2 < 32) { const int nb = (kt + 2) % 3; PROJ_STAGE(kt + 2, nb) }

        bf16x8 af2[4], bf2[4];
        #pragma unroll
        for (int mm = 0; mm < 4; ++mm)
            af2[mm] = *reinterpret_cast<const bf16x8*>(
                (const char*)&As[cur][0] + (wr * 64 + mm * 16 + l15) * 64 + rdx);
        #pragma unroll
        for (int nn = 0; nn < 4; ++nn)
            bf2[nn] = *reinterpret_cast<const bf16x8*>(
                (const char*)&Bs[cur][0] + (wc * 64 + nn * 16 + l15) * 64 + rdx);
        #pragma unroll
        for (int mm = 0; mm < 4; ++mm)
            #pragma unroll
            for (int nn = 0; nn < 4; ++nn)
                acc[mm][nn] = __builtin_amdgcn_mfma_f32_16x16x32_bf16(af2[mm], bf2[nn], acc[mm][nn], 0, 0, 0);

        if (kt < 30)       { WAIT_BARRIER(4) }
        else if (kt == 30) { WAIT_BARRIER(0) }
    }
#undef PROJ_STAGE

    #pragma unroll
    for (int mm = 0; mm < 4; ++mm) {
        #pragma unroll
        for (int nn = 0; nn < 4; ++nn) {
            const int gcol = n0 + wc * 64 + nn * 16 + l15;
            const float bv = bias[gcol];
            #pragma unroll
            for (int r = 0; r < 4; ++r) {
                const int grow = m0 + wr * 64 + mm * 16 + lhi * 4 + r;
                Co[(size_t)grow * EE + gcol] = acc[mm][nn][r] + bv;
            }
        }
    }
}

// Flash attention, QBLK=128 (8 waves x 16 q-rows), causal-paired over 8 pairs
// (t & 15-t -> 34 k-tiles/block), XCD-swizzled, exp2-domain ZERO-SHIFT softmax.
// Each K/V 64-row tile serves 128 q-rows: staging instrs + barriers per unit work
// halved vs QBLK=64. LDS 40KB: Ks 8KB single, Vs 16KB double, Ps 16KB (8 waves).
// Per tile: QK^T(Ks) -> barrierA -> stage K/V(kt+1) (1 gload/thr each) ->
// mask(last 2 tiles)+exp2+Ps+PV -> sum -> barrierB. Fully-masked waves produce
// P=0 (exp2(-1e30)=0) -> harmless under zero-shift softmax.
__global__ __launch_bounds__(512, 2)
void attn_kernel(const short* __restrict__ Q, const short* __restrict__ K,
                 const short* __restrict__ Vt, short* __restrict__ CTX)
{
    __shared__ short Ks[4096];      // 64 rows x 128B, XOR-16B swizzled (single buffer)
    __shared__ short Vs[2][4096];   // 64 d-rows x 128B, XOR-16B swizzled (double buffer)
    __shared__ short Ps[8][1024];   // per-wave P 16x64, XOR-swizzled rows of 128B
    const int tid  = threadIdx.x;
    const int lane = tid & 63, wid = tid >> 6;   // wid 0..7
    const int l15 = lane & 15, lhi = lane >> 4;
    // XCD swizzle: 8 pair-blocks of one bh on one XCD; 8 heads per XCD
    const int bid  = blockIdx.x;
    const int bh   = (bid & 7) * 8 + ((bid >> 3) & 7);
    const int pair = bid >> 6;                   // 0..7
    const int b = bh >> 4, h = bh & 15;
    const size_t base = (size_t)bh * (SS * DD);
    const short* VtBase = Vt + (size_t)bh * (DD * SS);
    char* const pw = (char*)&Ps[wid][0];

    const int srow = lane >> 3;
    const int scol = 8 * ((lane & 7) ^ srow);   // elems; LDS[row][X] = src[row][X ^ ((row&7)<<4)]

    for (int phase = 0; phase < 2; ++phase) {
        const int t = phase ? (15 - pair) : pair;   // q-tile index (128 rows)
        const int q0 = t * 128;
        const int qbase = q0 + wid * 16;
        const int nkt = 2 * t + 2;                  // k-tiles of 64

        bf16x8 qa[2];
        qa[0] = *reinterpret_cast<const bf16x8*>(&Q[base + (size_t)(qbase + l15) * DD + lhi * 8]);
        qa[1] = *reinterpret_cast<const bf16x8*>(&Q[base + (size_t)(qbase + l15) * DD + 32 + lhi * 8]);

        f32x4 o[4] = {};
        float lrow[4] = {0.f, 0.f, 0.f, 0.f};

        // prologue: wave w stages chunk w of K(0) and V(0) (1 gload each)
        gload16(&K     [base + (size_t)(wid * 8 + srow) * DD + scol], (char*)Ks + wid * 1024);
        gload16(&VtBase[(size_t)(wid * 8 + srow) * SS + scol],        (char*)&Vs[0][0] + wid * 1024);
        __syncthreads();

        for (int kt = 0; kt < nkt; ++kt) {
            const int cur = kt & 1;
            const int k0 = kt * 64;

            // QK^T from Ks: 4 col-groups x 2 k-steps (swizzled conflict-free ds_read_b128)
            f32x4 sc[4];
            #pragma unroll
            for (int n = 0; n < 4; ++n) {
                const int row = n * 16 + l15;
                f32x4 cacc = {};
                #pragma unroll
                for (int ks = 0; ks < 2; ++ks) {
                    const int byteoff = (ks * 64 + lhi * 16) ^ ((l15 & 7) << 4);
                    bf16x8 kb = *reinterpret_cast<const bf16x8*>((const char*)Ks + row * 128 + byteoff);
                    cacc = __builtin_amdgcn_mfma_f32_16x16x32_bf16(qa[ks], kb, cacc, 0, 0, 0);
                }
                sc[n] = cacc;
            }

            __syncthreads();   // barrier A: Ks consumed by all waves

            // stage NEXT K and V (latency hides under exp2 + PV below)
            if (kt + 1 < nkt) {
                const int k1 = k0 + 64;
                gload16(&K     [base + (size_t)(k1 + wid * 8 + srow) * DD + scol], (char*)Ks + wid * 1024);
                gload16(&VtBase[(size_t)(wid * 8 + srow) * SS + k1 + scol], (char*)&Vs[cur ^ 1][0] + wid * 1024);
            }

            // causal mask: needed when this k-tile reaches past the wave's first row
            if (k0 + 63 > qbase) {
                #pragma unroll
                for (int n = 0; n < 4; ++n) {
                    const int col = k0 + n * 16 + l15;
                    #pragma unroll
                    for (int r = 0; r < 4; ++r) {
                        const int qrow = qbase + lhi * 4 + r;
                        if (col > qrow) sc[n][r] = -1e30f;
                    }
                }
            }
            // zero-shift softmax numerator: P = exp2(sc) directly
            #pragma unroll
            for (int n = 0; n < 4; ++n)
                #pragma unroll
                for (int r = 0; r < 4; ++r) sc[n][r] = __builtin_amdgcn_exp2f(sc[n][r]);
            #pragma unroll
            for (int n = 0; n < 4; ++n)
                #pragma unroll
                for (int r = 0; r < 4; ++r) {
                    const int q = lhi * 4 + r;
                    const int cb = (n * 32 + l15 * 2) ^ ((q & 7) << 4);
                    *reinterpret_cast<short*>(pw + q * 128 + cb) = f2bf_fast(sc[n][r]);
                }
            bf16x8 pa[2];
            #pragma unroll
            for (int ks = 0; ks < 2; ++ks)
                pa[ks] = *reinterpret_cast<const bf16x8*>(
                    pw + l15 * 128 + ((ks * 64 + lhi * 16) ^ ((l15 & 7) << 4)));
            // PV from Vs[cur]
            #pragma unroll
            for (int dg = 0; dg < 4; ++dg) {
                const int row = dg * 16 + l15;
                #pragma unroll
                for (int ks = 0; ks < 2; ++ks) {
                    const int byteoff = (ks * 64 + lhi * 16) ^ ((l15 & 7) << 4);
                    bf16x8 vb = *reinterpret_cast<const bf16x8*>((const char*)&Vs[cur][0] + row * 128 + byteoff);
                    o[dg] = __builtin_amdgcn_mfma_f32_16x16x32_bf16(pa[ks], vb, o[dg], 0, 0, 0);
                }
            }
            // denominator accumulation (independent of PV; overlaps MFMA)
            float tsum[4];
            #pragma unroll
            for (int r = 0; r < 4; ++r)
                tsum[r] = (sc[0][r] + sc[1][r]) + (sc[2][r] + sc[3][r]);
            ROW_REDUCE(tsum, opsum)
            #pragma unroll
            for (int r = 0; r < 4; ++r) lrow[r] += tsum[r];

            __syncthreads();   // barrier B: drains K/V gloads; Vs[cur]/Ps readers done
        }

        // epilogue: CTX[b][s][h*64+d] bf16
        #pragma unroll
        for (int dg = 0; dg < 4; ++dg)
            #pragma unroll
            for (int r = 0; r < 4; ++r) {
                int s = qbase + lhi * 4 + r;
                float val = o[dg][r] / lrow[r];
                CTX[(size_t)(b * SS + s) * EE + h * DD + dg * 16 + l15] = f2bf(val);
            }
    }
}

extern "C" void kernel_launch(void* const* d_in, const int* in_sizes, int n_in,
                              void* d_out, int out_size, void* d_ws, size_t ws_size,
                              hipStream_t stream) {
    const float* hs     = (const float*)d_in[0];  // [B,S,E]
    const float* attn_w = (const float*)d_in[1];  // [E,3E]
    const float* attn_b = (const float*)d_in[2];  // [3E]
    const float* proj_w = (const float*)d_in[3];  // [E,E]
    const float* proj_b = (const float*)d_in[4];  // [E]
    float* out = (float*)d_out;

    char* ws = (char*)d_ws;
    short* Xb    = (short*)(ws + 0);          // 16.78 MB bf16 X; reused as CTX
    short* WqkvT = (short*)(ws + 16777216);   //  6.29 MB [3E][E] bf16
    short* WprojT= (short*)(ws + 23068672);   //  2.10 MB [E][E] bf16
    short* Qb    = (short*)(ws + 25165824);   // 16.78 MB [B*H][S][D]
    short* Kb    = (short*)(ws + 41943040);   // 16.78 MB [B*H][S][D]
    short* Vb    = (short*)(ws + 58720256);   // 16.78 MB [B*H][D][S]  (transposed)
    short* CTX   = Xb;

    cast_kernel<<<dim3(2048), dim3(256), 0, stream>>>(hs, Xb, (BB * SS * EE) / 4);
    transpose_cast_kernel<<<dim3(3 * EE / 32, EE / 32), dim3(256), 0, stream>>>(attn_w, WqkvT, 3 * EE, EE);
    transpose_cast_kernel<<<dim3(EE / 32, EE / 32), dim3(256), 0, stream>>>(proj_w, WprojT, EE, EE);

    gemm_qkv<<<dim3(3 * EE / 256, BB * SS / 128), dim3(512), 0, stream>>>(
        Xb, WqkvT, attn_b, Qb, Kb, Vb);

    attn_kernel<<<dim3(512), dim3(512), 0, stream>>>(Qb, Kb, Vb, CTX);

    gemm_proj<<<dim3(EE / 128, BB * SS / 128), dim3(256), 0, stream>>>(
        CTX, WprojT, proj_b, out);
}